// Round 1
// baseline (684.026 us; speedup 1.0000x reference)
//
#include <hip/hip_runtime.h>
#include <stdint.h>

#define N_NODES 100000
#define N_EDGES 1600000
#define N_SCAN_BLOCKS ((N_NODES + 1023) / 1024)   // 98
#define N_TILES (N_NODES / 16)                    // 6250 (exact: 100000 % 16 == 0)

typedef __attribute__((ext_vector_type(8))) short bf16x8;
typedef __attribute__((ext_vector_type(4))) float f32x4;

__device__ __forceinline__ uint32_t f2bf(float f) {
  uint32_t u = __float_as_uint(f);
  u += 0x7fffu + ((u >> 16) & 1);   // RNE
  return u >> 16;
}
__device__ __forceinline__ float bf_lo(uint32_t v) { return __uint_as_float(v << 16); }
__device__ __forceinline__ float bf_hi(uint32_t v) { return __uint_as_float(v & 0xffff0000u); }
__device__ __forceinline__ uint32_t pack2(float a, float b) { return f2bf(a) | (f2bf(b) << 16); }

// ---------- CSR build ----------
__global__ void k_hist(const int* __restrict__ dst, int* __restrict__ deg) {
  int e = blockIdx.x * 256 + threadIdx.x;
  if (e < N_EDGES) atomicAdd(&deg[dst[e]], 1);
}

__global__ __launch_bounds__(256) void k_scan_local(const int* __restrict__ deg,
                                                    int* __restrict__ row_ptr,
                                                    int* __restrict__ blocksum) {
  __shared__ int lds[256];
  int base = blockIdx.x * 1024 + threadIdx.x * 4;
  int v0 = (base     < N_NODES) ? deg[base]     : 0;
  int v1 = (base + 1 < N_NODES) ? deg[base + 1] : 0;
  int v2 = (base + 2 < N_NODES) ? deg[base + 2] : 0;
  int v3 = (base + 3 < N_NODES) ? deg[base + 3] : 0;
  int tsum = v0 + v1 + v2 + v3;
  lds[threadIdx.x] = tsum;
  __syncthreads();
  for (int off = 1; off < 256; off <<= 1) {
    int t = (threadIdx.x >= (unsigned)off) ? lds[threadIdx.x - off] : 0;
    __syncthreads();
    lds[threadIdx.x] += t;
    __syncthreads();
  }
  int run = lds[threadIdx.x] - tsum;
  if (base     < N_NODES) row_ptr[base]     = run;            run += v0;
  if (base + 1 < N_NODES) row_ptr[base + 1] = run;            run += v1;
  if (base + 2 < N_NODES) row_ptr[base + 2] = run;            run += v2;
  if (base + 3 < N_NODES) row_ptr[base + 3] = run;
  if (threadIdx.x == 255) blocksum[blockIdx.x] = lds[255];
}

__global__ __launch_bounds__(128) void k_scan_blocks(int* __restrict__ blocksum) {
  __shared__ int lds[128];
  int v = (threadIdx.x < N_SCAN_BLOCKS) ? blocksum[threadIdx.x] : 0;
  lds[threadIdx.x] = v;
  __syncthreads();
  for (int off = 1; off < 128; off <<= 1) {
    int t = (threadIdx.x >= (unsigned)off) ? lds[threadIdx.x - off] : 0;
    __syncthreads();
    lds[threadIdx.x] += t;
    __syncthreads();
  }
  if (threadIdx.x < N_SCAN_BLOCKS) blocksum[threadIdx.x] = lds[threadIdx.x] - v;
}

__global__ __launch_bounds__(256) void k_scan_add(int* __restrict__ row_ptr,
                                                  const int* __restrict__ blocksum) {
  int i = blockIdx.x * 256 + threadIdx.x;
  if (i < N_NODES) row_ptr[i] += blocksum[i >> 10];
  if (i == 0) row_ptr[N_NODES] = N_EDGES;
}

__global__ void k_scatter(const int* __restrict__ src, const int* __restrict__ dst,
                          const float* __restrict__ w, const int* __restrict__ row_ptr,
                          int* __restrict__ fill, int2* __restrict__ rec) {
  int e = blockIdx.x * 256 + threadIdx.x;
  if (e < N_EDGES) {
    int d = dst[e];
    int pos = row_ptr[d] + atomicAdd(&fill[d], 1);
    rec[pos] = make_int2(src[e], __float_as_int(w[e]));
  }
}

// ---------- pack fp32 weights -> bf16, transposed [n][k], XOR-swizzled ----------
// Swizzle: element (n,k) stored at n*K + (k ^ ((n&7)<<3))  (byte ^= (n&7)<<4).
// LDS staging is then a LINEAR copy of this image; only the ds_read applies the XOR,
// making the 512B/256B-row-stride ds_read_b128 pattern ~2-way (free) instead of 16-way.
__global__ void k_pack(const float* __restrict__ w1, const float* __restrict__ wp,
                       const float* __restrict__ w2, uint16_t* __restrict__ wT1,
                       uint16_t* __restrict__ wTc) {
  int i = blockIdx.x * 256 + threadIdx.x;
  if (i < 128 * 256) {            // wT1: n in [0,128), k in [0,256)
    int n = i >> 8, k = i & 255;
    wT1[n * 256 + (k ^ ((n & 7) << 3))] = (uint16_t)f2bf(w1[k * 128 + n]);
  }
  int j = i - 128 * 256;
  if (j >= 0 && j < 128 * 128) {  // wTc: n in [0,128), k in [0,128)
    int n = j >> 7, k = j & 127;
    wTc[n * 128 + (k ^ ((n & 7) << 3))] =
        (uint16_t)f2bf((n < 64) ? wp[k * 64 + n] : w2[k * 64 + (n - 64)]);
  }
}

// ---------- GEMM1: A[100000,256]fp32 @ W[256,128]bf16 -> C[100000,128]bf16 ----------
// B-stationary: whole swizzled wT1 (64 KB) staged in LDS once per block; persistent
// grid-stride tile loop with double-buffered register A-prefetch (16 KB/wave always
// in flight). 512 blocks = 2 blocks/CU (LDS-limited), 8 waves/CU.
#define G1_LOAD(buf, tt)                                                        \
  {                                                                             \
    const float* ap_ = A + ((size_t)(tt) * 16 + mcol) * 256 + quad * 8;         \
    _Pragma("unroll") for (int u_ = 0; u_ < 8; u_++) {                          \
      buf[2 * u_]     = *(const float4*)(ap_ + u_ * 32);                        \
      buf[2 * u_ + 1] = *(const float4*)(ap_ + u_ * 32 + 4);                    \
    }                                                                           \
  }

#define G1_COMP(buf, tt)                                                        \
  {                                                                             \
    f32x4 acc[8];                                                               \
    _Pragma("unroll") for (int nt_ = 0; nt_ < 8; nt_++)                         \
        acc[nt_] = (f32x4){0.f, 0.f, 0.f, 0.f};                                 \
    _Pragma("unroll") for (int it_ = 0; it_ < 8; it_++) {                       \
      float4 lo_ = buf[2 * it_], hi_ = buf[2 * it_ + 1];                        \
      bf16x8 a_;                                                                \
      a_[0] = (short)f2bf(lo_.x); a_[1] = (short)f2bf(lo_.y);                   \
      a_[2] = (short)f2bf(lo_.z); a_[3] = (short)f2bf(lo_.w);                   \
      a_[4] = (short)f2bf(hi_.x); a_[5] = (short)f2bf(hi_.y);                   \
      a_[6] = (short)f2bf(hi_.z); a_[7] = (short)f2bf(hi_.w);                   \
      _Pragma("unroll") for (int nt_ = 0; nt_ < 8; nt_++) {                     \
        bf16x8 b_ = *(const bf16x8*)(bp + nt_ * 4096 +                          \
                                     ((it_ * 32 + quad * 8) ^ xsw));            \
        acc[nt_] = __builtin_amdgcn_mfma_f32_16x16x32_bf16(a_, b_, acc[nt_],    \
                                                           0, 0, 0);            \
      }                                                                         \
    }                                                                           \
    _Pragma("unroll") for (int r_ = 0; r_ < 4; r_++) {                          \
      int row_ = (tt) * 16 + quad * 4 + r_;                                     \
      _Pragma("unroll") for (int nt_ = 0; nt_ < 8; nt_++)                       \
        C[(size_t)row_ * 128 + nt_ * 16 + mcol] = (uint16_t)f2bf(acc[nt_][r_]); \
    }                                                                           \
  }

__global__ __launch_bounds__(256, 2) void k_gemm1(const float* __restrict__ A,
                                                  const uint16_t* __restrict__ wTs,
                                                  uint16_t* __restrict__ C) {
  __shared__ uint16_t bs[128 * 256];   // 64 KB swizzled B image
  {
    const float4* s = (const float4*)wTs;
    float4* d = (float4*)bs;
#pragma unroll 4
    for (int i = threadIdx.x; i < 4096; i += 256) d[i] = s[i];
  }
  __syncthreads();
  const int lane = threadIdx.x & 63;
  const int quad = lane >> 4, mcol = lane & 15;
  const int xsw = (mcol & 7) << 3;
  const uint16_t* bp = bs + mcol * 256;
  const int NW = gridDim.x * 4;

  int t0 = blockIdx.x * 4 + (threadIdx.x >> 6);
  if (t0 >= N_TILES) return;
  float4 bufA[16], bufB[16];
  G1_LOAD(bufA, t0);
  for (;;) {
    int t1 = t0 + NW;
    if (t1 >= N_TILES) { G1_COMP(bufA, t0); break; }
    G1_LOAD(bufB, t1);
    G1_COMP(bufA, t0);
    t0 = t1 + NW;
    if (t0 >= N_TILES) { G1_COMP(bufB, t1); break; }
    G1_LOAD(bufA, t0);
    G1_COMP(bufB, t1);
  }
}

// ---------- GEMM2: A[100000,128]bf16 @ W[128,128]bf16 -> C[100000,128]bf16 ----------
// Same structure: 32 KB LDS B, 1024 blocks = 4 blocks/CU, double-buffered A.
#define G2_LOAD(buf, tt)                                                        \
  {                                                                             \
    const uint16_t* ap_ = A + ((size_t)(tt) * 16 + mcol) * 128 + quad * 8;      \
    _Pragma("unroll") for (int u_ = 0; u_ < 4; u_++)                            \
      buf[u_] = *(const bf16x8*)(ap_ + u_ * 32);                                \
  }

#define G2_COMP(buf, tt)                                                        \
  {                                                                             \
    f32x4 acc[8];                                                               \
    _Pragma("unroll") for (int nt_ = 0; nt_ < 8; nt_++)                         \
        acc[nt_] = (f32x4){0.f, 0.f, 0.f, 0.f};                                 \
    _Pragma("unroll") for (int it_ = 0; it_ < 4; it_++) {                       \
      _Pragma("unroll") for (int nt_ = 0; nt_ < 8; nt_++) {                     \
        bf16x8 b_ = *(const bf16x8*)(bp + nt_ * 2048 +                          \
                                     ((it_ * 32 + quad * 8) ^ xsw));            \
        acc[nt_] = __builtin_amdgcn_mfma_f32_16x16x32_bf16(buf[it_], b_,        \
                                                           acc[nt_], 0, 0, 0); \
      }                                                                         \
    }                                                                           \
    _Pragma("unroll") for (int r_ = 0; r_ < 4; r_++) {                          \
      int row_ = (tt) * 16 + quad * 4 + r_;                                     \
      _Pragma("unroll") for (int nt_ = 0; nt_ < 8; nt_++)                       \
        C[(size_t)row_ * 128 + nt_ * 16 + mcol] = (uint16_t)f2bf(acc[nt_][r_]); \
    }                                                                           \
  }

__global__ __launch_bounds__(256, 4) void k_gemm2(const uint16_t* __restrict__ A,
                                                  const uint16_t* __restrict__ wTs,
                                                  uint16_t* __restrict__ C) {
  __shared__ uint16_t bs[128 * 128];   // 32 KB swizzled B image
  {
    const float4* s = (const float4*)wTs;
    float4* d = (float4*)bs;
#pragma unroll 4
    for (int i = threadIdx.x; i < 2048; i += 256) d[i] = s[i];
  }
  __syncthreads();
  const int lane = threadIdx.x & 63;
  const int quad = lane >> 4, mcol = lane & 15;
  const int xsw = (mcol & 7) << 3;
  const uint16_t* bp = bs + mcol * 128;
  const int NW = gridDim.x * 4;

  int t0 = blockIdx.x * 4 + (threadIdx.x >> 6);
  if (t0 >= N_TILES) return;
  bf16x8 bufA[4], bufB[4];
  G2_LOAD(bufA, t0);
  for (;;) {
    int t1 = t0 + NW;
    if (t1 >= N_TILES) { G2_COMP(bufA, t0); break; }
    G2_LOAD(bufB, t1);
    G2_COMP(bufA, t0);
    t0 = t1 + NW;
    if (t0 >= N_TILES) { G2_COMP(bufB, t1); break; }
    G2_LOAD(bufA, t0);
    G2_COMP(bufB, t1);
  }
}

// ---------- SpMM: agg[r,:] = sum_e w_e * support[src_e,:]  (CSR, 1 wave/row, unroll 8) ----------
__global__ __launch_bounds__(256) void k_spmm(const uint16_t* __restrict__ sup,
                                              const int* __restrict__ row_ptr,
                                              const int2* __restrict__ rec,
                                              uint16_t* __restrict__ agg) {
  int row = blockIdx.x * 4 + (threadIdx.x >> 6);
  if (row >= N_NODES) return;
  int lane = threadIdx.x & 63;
  int s = row_ptr[row], e = row_ptr[row + 1];
  float a0 = 0.f, a1 = 0.f;
  int i = s;
  for (; i + 8 <= e; i += 8) {
    int2 r[8];
    uint32_t v[8];
#pragma unroll
    for (int u = 0; u < 8; u++) r[u] = rec[i + u];
#pragma unroll
    for (int u = 0; u < 8; u++)
      v[u] = *(const uint32_t*)(sup + (size_t)r[u].x * 128 + lane * 2);
#pragma unroll
    for (int u = 0; u < 8; u++) {
      float w = __int_as_float(r[u].y);
      a0 += w * bf_lo(v[u]);
      a1 += w * bf_hi(v[u]);
    }
  }
  for (; i < e; i++) {
    int2 r = rec[i];
    uint32_t v = *(const uint32_t*)(sup + (size_t)r.x * 128 + lane * 2);
    float w = __int_as_float(r.y);
    a0 += w * bf_lo(v);
    a1 += w * bf_hi(v);
  }
  *(uint32_t*)(agg + (size_t)row * 128 + lane * 2) = pack2(a0, a1);
}

// ---------- column sums (for PairNorm centering) ----------
__global__ __launch_bounds__(256) void k_colsum(const uint16_t* __restrict__ agg,
                                                float* __restrict__ cs) {
  __shared__ float sd[256];
  int col = threadIdx.x & 127, half = threadIdx.x >> 7;
  int r0 = blockIdx.x * 256;
  float local = 0.f;
  for (int r = r0 + half; r < r0 + 256 && r < N_NODES; r += 2)
    local += __uint_as_float(((uint32_t)agg[(size_t)r * 128 + col]) << 16);
  sd[threadIdx.x] = local;
  __syncthreads();
  if (threadIdx.x < 128) atomicAdd(&cs[col], sd[threadIdx.x] + sd[threadIdx.x + 128]);
}

// ---------- PairNorm-SI + ReLU, IN PLACE on agg (bf16) ----------
__global__ __launch_bounds__(256) void k_pn1(uint16_t* __restrict__ agg,
                                             const float* __restrict__ cs) {
  int row = blockIdx.x * 4 + (threadIdx.x >> 6);
  if (row >= N_NODES) return;
  int lane = threadIdx.x & 63;
  const float invn = 1.0f / (float)N_NODES;
  uint32_t v = *(const uint32_t*)(agg + (size_t)row * 128 + lane * 2);
  float h0 = bf_lo(v) - cs[lane * 2] * invn;
  float h1 = bf_hi(v) - cs[lane * 2 + 1] * invn;
  float ss = h0 * h0 + h1 * h1;
#pragma unroll
  for (int m = 1; m < 64; m <<= 1) ss += __shfl_xor(ss, m, 64);
  float rinv = rsqrtf(1e-6f + ss);
  *(uint32_t*)(agg + (size_t)row * 128 + lane * 2) =
      pack2(fmaxf(h0 * rinv, 0.f), fmaxf(h1 * rinv, 0.f));
}

// ---------- final: agg cols 0..63 -> pool1 (pairnorm+softmax), 64..127 -> enc2 (pairnorm+relu), fp32 out ----------
__global__ __launch_bounds__(256) void k_final(const uint16_t* __restrict__ agg,
                                               const float* __restrict__ cs,
                                               float* __restrict__ out) {
  int row = blockIdx.x * 4 + (threadIdx.x >> 6);
  if (row >= N_NODES) return;
  int lane = threadIdx.x & 63;
  const float invn = 1.0f / (float)N_NODES;
  uint32_t v = *(const uint32_t*)(agg + (size_t)row * 128 + lane * 2);
  float h0 = bf_lo(v) - cs[lane * 2] * invn;
  float h1 = bf_hi(v) - cs[lane * 2 + 1] * invn;
  float ss = h0 * h0 + h1 * h1;
#pragma unroll
  for (int m = 1; m < 32; m <<= 1) ss += __shfl_xor(ss, m, 64);
  float rinv = rsqrtf(1e-6f + ss);
  float p0 = h0 * rinv, p1 = h1 * rinv;
  if (lane < 32) {
    float mx = fmaxf(p0, p1);
#pragma unroll
    for (int m = 1; m < 32; m <<= 1) mx = fmaxf(mx, __shfl_xor(mx, m, 64));
    float e0 = __expf(p0 - mx), e1 = __expf(p1 - mx);
    float sum = e0 + e1;
#pragma unroll
    for (int m = 1; m < 32; m <<= 1) sum += __shfl_xor(sum, m, 64);
    float inv = 1.0f / sum;
    float2 o = {e0 * inv, e1 * inv};
    *(float2*)(out + (size_t)N_NODES * 64 + (size_t)row * 64 + lane * 2) = o;
  } else {
    int l = lane - 32;
    float2 o = {fmaxf(p0, 0.f), fmaxf(p1, 0.f)};
    *(float2*)(out + (size_t)row * 64 + l * 2) = o;
  }
}

extern "C" void kernel_launch(void* const* d_in, const int* in_sizes, int n_in,
                              void* d_out, int out_size, void* d_ws, size_t ws_size,
                              hipStream_t stream) {
  const float* x    = (const float*)d_in[0];
  const int*   esrc = (const int*)d_in[1];
  const int*   edst = (const int*)d_in[2];
  const float* ew   = (const float*)d_in[3];
  const float* w1   = (const float*)d_in[4];
  // d_in[5]=b1, d_in[7]=bp, d_in[9]=b2 are zero AND cancel under PairNorm centering
  const float* wp   = (const float*)d_in[6];
  const float* w2   = (const float*)d_in[8];
  float* out = (float*)d_out;

  char* ws = (char*)d_ws;
  size_t off = 0;
  auto alloc = [&](size_t bytes) {
    char* p = ws + off;
    off += (bytes + 255) & ~(size_t)255;
    return p;
  };
  uint16_t* support = (uint16_t*)alloc((size_t)N_NODES * 128 * 2);  // bf16
  uint16_t* agg     = (uint16_t*)alloc((size_t)N_NODES * 128 * 2);  // bf16; reused as enc1 in place
  int2*     rec     = (int2*)alloc((size_t)N_EDGES * 8);            // packed {src, w}
  int*      row_ptr = (int*)alloc((size_t)(N_NODES + 1) * 4);
  int*      bsum    = (int*)alloc((size_t)N_SCAN_BLOCKS * 4);
  size_t zero_start = off;
  int*      deg     = (int*)alloc((size_t)N_NODES * 4);
  int*      fill    = (int*)alloc((size_t)N_NODES * 4);
  float*    cs      = (float*)alloc(256 * 4);
  size_t zero_bytes = off - zero_start;
  uint16_t* wT1     = (uint16_t*)alloc(128 * 256 * 2);
  uint16_t* wTc     = (uint16_t*)alloc(128 * 128 * 2);
  (void)ws_size; (void)in_sizes; (void)n_in; (void)out_size;

  hipMemsetAsync(deg, 0, zero_bytes, stream);

  // CSR build (reused by both SpMMs)
  k_hist<<<(N_EDGES + 255) / 256, 256, 0, stream>>>(edst, deg);
  k_scan_local<<<N_SCAN_BLOCKS, 256, 0, stream>>>(deg, row_ptr, bsum);
  k_scan_blocks<<<1, 128, 0, stream>>>(bsum);
  k_scan_add<<<(N_NODES + 255) / 256, 256, 0, stream>>>(row_ptr, bsum);
  k_scatter<<<(N_EDGES + 255) / 256, 256, 0, stream>>>(esrc, edst, ew, row_ptr, fill, rec);
  k_pack<<<192, 256, 0, stream>>>(w1, wp, w2, wT1, wTc);

  // Layer 1
  k_gemm1<<<512, 256, 0, stream>>>(x, wT1, support);
  k_spmm<<<(N_NODES + 3) / 4, 256, 0, stream>>>(support, row_ptr, rec, agg);
  k_colsum<<<(N_NODES + 255) / 256, 256, 0, stream>>>(agg, cs);
  k_pn1<<<(N_NODES + 3) / 4, 256, 0, stream>>>(agg, cs);  // agg := enc1 (in place)

  // Layer 2 (pool + enc fused: support_cat = enc1 @ [wp|w2])
  k_gemm2<<<1024, 256, 0, stream>>>(agg, wTc, support);
  k_spmm<<<(N_NODES + 3) / 4, 256, 0, stream>>>(support, row_ptr, rec, agg);
  k_colsum<<<(N_NODES + 255) / 256, 256, 0, stream>>>(agg, cs + 128);
  k_final<<<(N_NODES + 3) / 4, 256, 0, stream>>>(agg, cs + 128, out);
}